// Round 5
// baseline (141.486 us; speedup 1.0000x reference)
//
#include <hip/hip_runtime.h>
#include <hip/hip_bf16.h>

// AdaptiveFourierPositionEncoding — round 5: r3 structure exactly, occupancy
// isolation: 2048 -> 4096 waves (4/SIMD; r3's VGPR=124 already fits).
// Strided tile mapping (epoch-swept output) retained — it kept WRITE_SIZE
// ideal in r2/r3. Only grid/TPW changed vs r3.

#define NTOK   (8 * 32768)
#define NTILE  (NTOK / 16)        // 16384
#define NW     4096               // persistent waves (was 2048)
#define TPW    (NTILE / NW)       // 4 tiles per wave

typedef short  bf16x8 __attribute__((ext_vector_type(8)));
typedef float  f32x4  __attribute__((ext_vector_type(4)));

static __device__ __forceinline__ short f2bf(float f) {
    __hip_bfloat16 h = __float2bfloat16(f);   // RNE
    return __builtin_bit_cast(short, h);
}

__global__ __launch_bounds__(256, 4) void afpe_r5(
    const float* __restrict__ x, const int* __restrict__ pos,
    const float* __restrict__ fb, const float* __restrict__ ph,
    const float* __restrict__ aw, const float* __restrict__ ab,
    float* __restrict__ out)
{
    const int lane = threadIdx.x & 63;
    const int gw   = blockIdx.x * 4 + (threadIdx.x >> 6);  // 0..4095
    const int q    = lane >> 4;               // k-group / D-row group
    const int tt   = lane & 15;               // token-in-tile / A-row

    // A fragments: W[64][128] -> bf16, resident whole kernel.
    // A[m][c] elem i = W[16m + tt][q*8 + 32c + i]
    bf16x8 A[4][4];
    #pragma unroll
    for (int m = 0; m < 4; ++m) {
        #pragma unroll
        for (int c = 0; c < 4; ++c) {
            const float* wp = aw + (size_t)(16 * m + tt) * 128 + q * 8 + 32 * c;
            const float4 w0 = *(const float4*)wp;
            const float4 w1 = *(const float4*)(wp + 4);
            bf16x8 a;
            a[0] = f2bf(w0.x); a[1] = f2bf(w0.y); a[2] = f2bf(w0.z); a[3] = f2bf(w0.w);
            a[4] = f2bf(w1.x); a[5] = f2bf(w1.y); a[6] = f2bf(w1.z); a[7] = f2bf(w1.w);
            A[m][c] = a;
        }
    }
    // per-lane band params: bands q*4 + 16m + r (r=0..3)
    float4 fbv[4], phv[4], abv[4];
    #pragma unroll
    for (int m = 0; m < 4; ++m) {
        fbv[m] = *(const float4*)(fb + q * 4 + 16 * m);
        phv[m] = *(const float4*)(ph + q * 4 + 16 * m);
        abv[m] = *(const float4*)(ab + q * 4 + 16 * m);
    }

    // 3-slot tile pipeline: xf[s][2c+h] = x[tile][tt][q*8+32c+4h .. +3]
    float4 xf[3][8];
    int    pp[3];

    // prologue: tiles t0, t0+NW
    #pragma unroll
    for (int s = 0; s < 2; ++s) {
        const int t = gw + s * NW;
        const float* base = x + (size_t)t * 2048 + tt * 128 + q * 8;
        #pragma unroll
        for (int c = 0; c < 4; ++c) {
            xf[s][2 * c]     = *(const float4*)(base + 32 * c);
            xf[s][2 * c + 1] = *(const float4*)(base + 32 * c + 4);
        }
        pp[s] = pos[t * 16 + tt];
    }

    #pragma unroll
    for (int it = 0; it < TPW; ++it) {
        const int cur = it % 3;
        const int nxt = (it + 2) % 3;
        const int tile = gw + it * NW;

        // issue tile t+2 loads (clamped re-load of current tile past the end;
        // values unused)
        {
            int lt = tile + 2 * NW;
            if (lt >= NTILE) lt = tile;
            const float* base = x + (size_t)lt * 2048 + tt * 128 + q * 8;
            #pragma unroll
            for (int c = 0; c < 4; ++c) {
                xf[nxt][2 * c]     = *(const float4*)(base + 32 * c);
                xf[nxt][2 * c + 1] = *(const float4*)(base + 32 * c + 4);
            }
            pp[nxt] = pos[lt * 16 + tt];
        }

        // bf16 B fragments from current tile
        bf16x8 B[4];
        #pragma unroll
        for (int c = 0; c < 4; ++c) {
            const float4 b0 = xf[cur][2 * c], b1 = xf[cur][2 * c + 1];
            bf16x8 bv;
            bv[0] = f2bf(b0.x); bv[1] = f2bf(b0.y); bv[2] = f2bf(b0.z); bv[3] = f2bf(b0.w);
            bv[4] = f2bf(b1.x); bv[5] = f2bf(b1.y); bv[6] = f2bf(b1.z); bv[7] = f2bf(b1.w);
            B[c] = bv;
        }

        // logits: acc[m] reg r = logit[band 16m + q*4 + r][token tt]
        f32x4 acc[4];
        #pragma unroll
        for (int m = 0; m < 4; ++m) {
            acc[m][0] = abv[m].x; acc[m][1] = abv[m].y;
            acc[m][2] = abv[m].z; acc[m][3] = abv[m].w;
        }
        #pragma unroll
        for (int c = 0; c < 4; ++c) {
            #pragma unroll
            for (int m = 0; m < 4; ++m)
                acc[m] = __builtin_amdgcn_mfma_f32_16x16x32_bf16(A[m][c], B[c], acc[m], 0, 0, 0);
        }

        // softmax over 64 bands of token tt (lanes tt, tt+16, tt+32, tt+48)
        float e[4][4];
        float s = 0.f;
        #pragma unroll
        for (int m = 0; m < 4; ++m) {
            #pragma unroll
            for (int r = 0; r < 4; ++r) { e[m][r] = __expf(acc[m][r]); s += e[m][r]; }
        }
        s += __shfl_xor(s, 16, 64);
        s += __shfl_xor(s, 32, 64);
        const float rinv = 1.0f / s;

        // trig: f32 angle exactly as reference, f64 range-reduce to revolutions
        const float pf = (float)pp[cur];
        float sa[4][4], ca[4][4];
        #pragma unroll
        for (int m = 0; m < 4; ++m) {
            const float fq[4] = {fbv[m].x, fbv[m].y, fbv[m].z, fbv[m].w};
            const float pq[4] = {phv[m].x, phv[m].y, phv[m].z, phv[m].w};
            #pragma unroll
            for (int r = 0; r < 4; ++r) {
                float ang = pf * fq[r];
                ang = ang + pq[r];
                double td = (double)ang * 0.15915494309189535;  // 1/(2*pi)
                td -= floor(td);
                const float rev = (float)td;
                const float at  = e[m][r] * rinv;
                sa[m][r] = __builtin_amdgcn_sinf(rev) * at;
                ca[m][r] = __builtin_amdgcn_cosf(rev) * at;
            }
        }

        // out[tt][k] = x + {sin,cos}*attn ; chunk c's bands == acc[c]'s bands
        float* ob = out + (size_t)(tile * 16 + tt) * 128 + q * 8;
        #pragma unroll
        for (int c = 0; c < 4; ++c) {
            #pragma unroll
            for (int h = 0; h < 2; ++h) {
                const float4 xv = xf[cur][2 * c + h];
                float4 o;
                o.x = xv.x + sa[c][2 * h];
                o.y = xv.y + ca[c][2 * h];
                o.z = xv.z + sa[c][2 * h + 1];
                o.w = xv.w + ca[c][2 * h + 1];
                *(float4*)(ob + 32 * c + 4 * h) = o;
            }
        }
    }
}

extern "C" void kernel_launch(void* const* d_in, const int* in_sizes, int n_in,
                              void* d_out, int out_size, void* d_ws, size_t ws_size,
                              hipStream_t stream) {
    const float* x   = (const float*)d_in[0];
    const int*   pos = (const int*)d_in[1];
    const float* fb  = (const float*)d_in[2];
    const float* ph  = (const float*)d_in[3];
    const float* aw  = (const float*)d_in[4];
    const float* ab  = (const float*)d_in[5];
    float* out = (float*)d_out;

    // 1024 blocks x 4 waves = 4096 persistent waves (4/SIMD); 4 tiles each,
    // strided mapping: epoch-swept reads/writes as in r3.
    afpe_r5<<<1024, 256, 0, stream>>>(x, pos, fb, ph, aw, ab, out);
}

// Round 6
// 60.638 us; speedup vs baseline: 2.3333x; 2.3333x over previous
//
#include <hip/hip_runtime.h>
#include <hip/hip_bf16.h>

// AdaptiveFourierPositionEncoding — round 6: r5 body EXACTLY, one change:
// __launch_bounds__(256,2) instead of (256,4). Under (256,2) this body
// compiled to 124 VGPR (r3) -> fits 4 waves/SIMD honestly; (256,4) had
// invited the allocator down to 64 VGPR, poisoning r4/r5 with spill traffic
// (FETCH 66->230 MB, WRITE 131->255 MB). Grid stays 4096 waves.

#define NTOK   (8 * 32768)
#define NTILE  (NTOK / 16)        // 16384
#define NW     4096               // persistent waves
#define TPW    (NTILE / NW)       // 4 tiles per wave

typedef short  bf16x8 __attribute__((ext_vector_type(8)));
typedef float  f32x4  __attribute__((ext_vector_type(4)));

static __device__ __forceinline__ short f2bf(float f) {
    __hip_bfloat16 h = __float2bfloat16(f);   // RNE
    return __builtin_bit_cast(short, h);
}

__global__ __launch_bounds__(256, 2) void afpe_r6(
    const float* __restrict__ x, const int* __restrict__ pos,
    const float* __restrict__ fb, const float* __restrict__ ph,
    const float* __restrict__ aw, const float* __restrict__ ab,
    float* __restrict__ out)
{
    const int lane = threadIdx.x & 63;
    const int gw   = blockIdx.x * 4 + (threadIdx.x >> 6);  // 0..4095
    const int q    = lane >> 4;               // k-group / D-row group
    const int tt   = lane & 15;               // token-in-tile / A-row

    // A fragments: W[64][128] -> bf16, resident whole kernel.
    // A[m][c] elem i = W[16m + tt][q*8 + 32c + i]
    bf16x8 A[4][4];
    #pragma unroll
    for (int m = 0; m < 4; ++m) {
        #pragma unroll
        for (int c = 0; c < 4; ++c) {
            const float* wp = aw + (size_t)(16 * m + tt) * 128 + q * 8 + 32 * c;
            const float4 w0 = *(const float4*)wp;
            const float4 w1 = *(const float4*)(wp + 4);
            bf16x8 a;
            a[0] = f2bf(w0.x); a[1] = f2bf(w0.y); a[2] = f2bf(w0.z); a[3] = f2bf(w0.w);
            a[4] = f2bf(w1.x); a[5] = f2bf(w1.y); a[6] = f2bf(w1.z); a[7] = f2bf(w1.w);
            A[m][c] = a;
        }
    }
    // per-lane band params: bands q*4 + 16m + r (r=0..3)
    float4 fbv[4], phv[4], abv[4];
    #pragma unroll
    for (int m = 0; m < 4; ++m) {
        fbv[m] = *(const float4*)(fb + q * 4 + 16 * m);
        phv[m] = *(const float4*)(ph + q * 4 + 16 * m);
        abv[m] = *(const float4*)(ab + q * 4 + 16 * m);
    }

    // 3-slot tile pipeline: xf[s][2c+h] = x[tile][tt][q*8+32c+4h .. +3]
    float4 xf[3][8];
    int    pp[3];

    // prologue: tiles t0, t0+NW
    #pragma unroll
    for (int s = 0; s < 2; ++s) {
        const int t = gw + s * NW;
        const float* base = x + (size_t)t * 2048 + tt * 128 + q * 8;
        #pragma unroll
        for (int c = 0; c < 4; ++c) {
            xf[s][2 * c]     = *(const float4*)(base + 32 * c);
            xf[s][2 * c + 1] = *(const float4*)(base + 32 * c + 4);
        }
        pp[s] = pos[t * 16 + tt];
    }

    #pragma unroll
    for (int it = 0; it < TPW; ++it) {
        const int cur = it % 3;
        const int nxt = (it + 2) % 3;
        const int tile = gw + it * NW;

        // issue tile t+2 loads (clamped re-load of current tile past the end;
        // values unused)
        {
            int lt = tile + 2 * NW;
            if (lt >= NTILE) lt = tile;
            const float* base = x + (size_t)lt * 2048 + tt * 128 + q * 8;
            #pragma unroll
            for (int c = 0; c < 4; ++c) {
                xf[nxt][2 * c]     = *(const float4*)(base + 32 * c);
                xf[nxt][2 * c + 1] = *(const float4*)(base + 32 * c + 4);
            }
            pp[nxt] = pos[lt * 16 + tt];
        }

        // bf16 B fragments from current tile
        bf16x8 B[4];
        #pragma unroll
        for (int c = 0; c < 4; ++c) {
            const float4 b0 = xf[cur][2 * c], b1 = xf[cur][2 * c + 1];
            bf16x8 bv;
            bv[0] = f2bf(b0.x); bv[1] = f2bf(b0.y); bv[2] = f2bf(b0.z); bv[3] = f2bf(b0.w);
            bv[4] = f2bf(b1.x); bv[5] = f2bf(b1.y); bv[6] = f2bf(b1.z); bv[7] = f2bf(b1.w);
            B[c] = bv;
        }

        // logits: acc[m] reg r = logit[band 16m + q*4 + r][token tt]
        f32x4 acc[4];
        #pragma unroll
        for (int m = 0; m < 4; ++m) {
            acc[m][0] = abv[m].x; acc[m][1] = abv[m].y;
            acc[m][2] = abv[m].z; acc[m][3] = abv[m].w;
        }
        #pragma unroll
        for (int c = 0; c < 4; ++c) {
            #pragma unroll
            for (int m = 0; m < 4; ++m)
                acc[m] = __builtin_amdgcn_mfma_f32_16x16x32_bf16(A[m][c], B[c], acc[m], 0, 0, 0);
        }

        // softmax over 64 bands of token tt (lanes tt, tt+16, tt+32, tt+48)
        float e[4][4];
        float s = 0.f;
        #pragma unroll
        for (int m = 0; m < 4; ++m) {
            #pragma unroll
            for (int r = 0; r < 4; ++r) { e[m][r] = __expf(acc[m][r]); s += e[m][r]; }
        }
        s += __shfl_xor(s, 16, 64);
        s += __shfl_xor(s, 32, 64);
        const float rinv = 1.0f / s;

        // trig: f32 angle exactly as reference, f64 range-reduce to revolutions
        const float pf = (float)pp[cur];
        float sa[4][4], ca[4][4];
        #pragma unroll
        for (int m = 0; m < 4; ++m) {
            const float fq[4] = {fbv[m].x, fbv[m].y, fbv[m].z, fbv[m].w};
            const float pq[4] = {phv[m].x, phv[m].y, phv[m].z, phv[m].w};
            #pragma unroll
            for (int r = 0; r < 4; ++r) {
                float ang = pf * fq[r];
                ang = ang + pq[r];
                double td = (double)ang * 0.15915494309189535;  // 1/(2*pi)
                td -= floor(td);
                const float rev = (float)td;
                const float at  = e[m][r] * rinv;
                sa[m][r] = __builtin_amdgcn_sinf(rev) * at;
                ca[m][r] = __builtin_amdgcn_cosf(rev) * at;
            }
        }

        // out[tt][k] = x + {sin,cos}*attn ; chunk c's bands == acc[c]'s bands
        float* ob = out + (size_t)(tile * 16 + tt) * 128 + q * 8;
        #pragma unroll
        for (int c = 0; c < 4; ++c) {
            #pragma unroll
            for (int h = 0; h < 2; ++h) {
                const float4 xv = xf[cur][2 * c + h];
                float4 o;
                o.x = xv.x + sa[c][2 * h];
                o.y = xv.y + ca[c][2 * h];
                o.z = xv.z + sa[c][2 * h + 1];
                o.w = xv.w + ca[c][2 * h + 1];
                *(float4*)(ob + 32 * c + 4 * h) = o;
            }
        }
    }
}

extern "C" void kernel_launch(void* const* d_in, const int* in_sizes, int n_in,
                              void* d_out, int out_size, void* d_ws, size_t ws_size,
                              hipStream_t stream) {
    const float* x   = (const float*)d_in[0];
    const int*   pos = (const int*)d_in[1];
    const float* fb  = (const float*)d_in[2];
    const float* ph  = (const float*)d_in[3];
    const float* aw  = (const float*)d_in[4];
    const float* ab  = (const float*)d_in[5];
    float* out = (float*)d_out;

    // 1024 blocks x 4 waves = 4096 persistent waves; VGPR<=128 under
    // launch_bounds(256,2) -> honest 4 waves/SIMD, no spills.
    afpe_r6<<<1024, 256, 0, stream>>>(x, pos, fb, ph, aw, ab, out);
}

// Round 7
// 57.383 us; speedup vs baseline: 2.4656x; 1.0567x over previous
//
#include <hip/hip_runtime.h>
#include <hip/hip_bf16.h>

// AdaptiveFourierPositionEncoding — round 7: kill store->load vmcnt coupling.
// One 16-token tile per wave, NO loop: per wave 9 loads -> compute -> 8
// stores -> end. No load follows a store in any wave, so vmcnt waits never
// drain the write queue (the r2/r3/r6 serializer). W frags + params in
// per-block LDS (lgkmcnt path, uncoupled). 4096 blocks x 4 waves = 16384
// waves, one tile each.

#define NTOK  (8 * 32768)
#define NTILE (NTOK / 16)     // 16384
#define WPB   4
#define NBLK  (NTILE / WPB)   // 4096

typedef short  bf16x8 __attribute__((ext_vector_type(8)));
typedef float  f32x4  __attribute__((ext_vector_type(4)));

static __device__ __forceinline__ short f2bf(float f) {
    __hip_bfloat16 h = __float2bfloat16(f);   // RNE
    return __builtin_bit_cast(short, h);
}

__global__ __launch_bounds__(256, 3) void afpe_r7(
    const float* __restrict__ x, const int* __restrict__ pos,
    const float* __restrict__ fb, const float* __restrict__ ph,
    const float* __restrict__ aw, const float* __restrict__ ab,
    float* __restrict__ out)
{
    // W fragments, fragment-linear: chunk(m,c) @ (m*4+c)*1024 + lane*16
    // (layout verified correct in r4).
    __shared__ __align__(16) char wlds[16384];
    __shared__ float pfb[64], pph[64], pab[64];

    const int tid  = threadIdx.x;
    const int lane = tid & 63;
    const int q    = lane >> 4;     // k-group / D-row group
    const int tt   = lane & 15;     // token-in-tile / A-row

    // ---- one-time staging: W -> bf16 frags in LDS, params -> LDS ----
    #pragma unroll
    for (int g0 = 0; g0 < 4; ++g0) {
        const int g  = g0 * 256 + tid;          // granule 0..1023
        const int mc = g >> 6, l = g & 63;
        const int sm = mc >> 2, sc = mc & 3, sq = l >> 4, st = l & 15;
        const float* wp = aw + (size_t)(16 * sm + st) * 128 + sq * 8 + 32 * sc;
        const float4 w0 = *(const float4*)wp;
        const float4 w1 = *(const float4*)(wp + 4);
        bf16x8 a;
        a[0] = f2bf(w0.x); a[1] = f2bf(w0.y); a[2] = f2bf(w0.z); a[3] = f2bf(w0.w);
        a[4] = f2bf(w1.x); a[5] = f2bf(w1.y); a[6] = f2bf(w1.z); a[7] = f2bf(w1.w);
        *(bf16x8*)(wlds + mc * 1024 + l * 16) = a;
    }
    if (tid < 64) { pfb[tid] = fb[tid]; pph[tid] = ph[tid]; pab[tid] = ab[tid]; }
    __syncthreads();

    // ---- one tile per wave ----
    const int tile = blockIdx.x * WPB + (tid >> 6);

    // x loads: lane (q,tt) reads token row tt, cols q*8 + 32c + 4h .. +3
    const float* base = x + (size_t)tile * 2048 + tt * 128 + q * 8;
    float4 xf[8];
    #pragma unroll
    for (int c = 0; c < 4; ++c) {
        xf[2 * c]     = *(const float4*)(base + 32 * c);
        xf[2 * c + 1] = *(const float4*)(base + 32 * c + 4);
    }
    const int p = pos[tile * 16 + tt];

    // logits: acc[m] reg r = logit[band 16m + 4q + r][token tt]
    f32x4 acc[4];
    #pragma unroll
    for (int m = 0; m < 4; ++m) {
        const float4 abv = *(const float4*)&pab[16 * m + 4 * q];
        acc[m][0] = abv.x; acc[m][1] = abv.y; acc[m][2] = abv.z; acc[m][3] = abv.w;
    }
    #pragma unroll
    for (int c = 0; c < 4; ++c) {
        const float4 b0 = xf[2 * c], b1 = xf[2 * c + 1];
        bf16x8 B;
        B[0] = f2bf(b0.x); B[1] = f2bf(b0.y); B[2] = f2bf(b0.z); B[3] = f2bf(b0.w);
        B[4] = f2bf(b1.x); B[5] = f2bf(b1.y); B[6] = f2bf(b1.z); B[7] = f2bf(b1.w);
        #pragma unroll
        for (int m = 0; m < 4; ++m) {
            const bf16x8 A = *(const bf16x8*)(wlds + (m * 4 + c) * 1024 + lane * 16);
            acc[m] = __builtin_amdgcn_mfma_f32_16x16x32_bf16(A, B, acc[m], 0, 0, 0);
        }
    }

    // softmax over 64 bands of token tt (partners: lanes tt + 16k)
    float e[4][4];
    float s = 0.f;
    #pragma unroll
    for (int m = 0; m < 4; ++m) {
        #pragma unroll
        for (int r = 0; r < 4; ++r) { e[m][r] = __expf(acc[m][r]); s += e[m][r]; }
    }
    s += __shfl_xor(s, 16, 64);
    s += __shfl_xor(s, 32, 64);
    const float rinv = 1.0f / s;

    // per-chunk trig + epilogue + store
    const float pf = (float)p;
    float* ob = out + (size_t)(tile * 16 + tt) * 128 + q * 8;
    #pragma unroll
    for (int c = 0; c < 4; ++c) {
        const float4 fq4 = *(const float4*)&pfb[16 * c + 4 * q];
        const float4 ph4 = *(const float4*)&pph[16 * c + 4 * q];
        const float fq[4] = {fq4.x, fq4.y, fq4.z, fq4.w};
        const float pq[4] = {ph4.x, ph4.y, ph4.z, ph4.w};
        float sa[4], ca[4];
        #pragma unroll
        for (int r = 0; r < 4; ++r) {
            float ang = pf * fq[r];
            ang = ang + pq[r];
            double td = (double)ang * 0.15915494309189535;  // 1/(2*pi)
            td -= floor(td);
            const float rev = (float)td;
            const float at  = e[c][r] * rinv;
            sa[r] = __builtin_amdgcn_sinf(rev) * at;
            ca[r] = __builtin_amdgcn_cosf(rev) * at;
        }
        const float4 xv0 = xf[2 * c], xv1 = xf[2 * c + 1];
        float4 o0, o1;
        o0.x = xv0.x + sa[0]; o0.y = xv0.y + ca[0];
        o0.z = xv0.z + sa[1]; o0.w = xv0.w + ca[1];
        o1.x = xv1.x + sa[2]; o1.y = xv1.y + ca[2];
        o1.z = xv1.z + sa[3]; o1.w = xv1.w + ca[3];
        *(float4*)(ob + 32 * c)     = o0;
        *(float4*)(ob + 32 * c + 4) = o1;
    }
}

extern "C" void kernel_launch(void* const* d_in, const int* in_sizes, int n_in,
                              void* d_out, int out_size, void* d_ws, size_t ws_size,
                              hipStream_t stream) {
    const float* x   = (const float*)d_in[0];
    const int*   pos = (const int*)d_in[1];
    const float* fb  = (const float*)d_in[2];
    const float* ph  = (const float*)d_in[3];
    const float* aw  = (const float*)d_in[4];
    const float* ab  = (const float*)d_in[5];
    float* out = (float*)d_out;

    // 4096 blocks x 256 threads = 16384 waves, one 16-token tile each.
    afpe_r7<<<NBLK, 256, 0, stream>>>(x, pos, fb, ph, aw, ab, out);
}